// Round 1
// baseline (7786.639 us; speedup 1.0000x reference)
//
#include <hip/hip_runtime.h>

#define U_N 400000
#define I_N 400000
#define DD  64
#define BB  2
#define EE  2000000

// d_out float layout (all f32):
//   [0,              U*D)                user_embedding (mean)   <- also temp tw_item
//   [U*D,            2*U*D)              item_embedding (mean)   <- also temp tw_user
//   [2*U*D,          2*U*D + B*U*D)      user_embeddings [B,U,D] <- accumulator for t_b (user side)
//   [2*U*D + B*U*D,  2*U*D + 2*B*U*D)   item_embeddings [B,I,D] <- accumulator for t_b (item side)

// ---------------- tw = X @ W  (X:[n,64] f32, W:[64,64] f32) ----------------
// block = 128 threads = 2 waves; each wave computes 64 rows (lane = row),
// acc[64] = all 64 output columns per lane. W reads are wave-uniform ->
// compiler scalarizes to s_load; X staged in LDS with +1 pad (conflict-free).
__global__ __launch_bounds__(128) void rowgemm(const float* __restrict__ X,
                                               const float* __restrict__ Wm,
                                               float* __restrict__ Y, int n) {
    __shared__ float xs[2][64][65];
    const int wv = threadIdx.x >> 6;
    const int ln = threadIdx.x & 63;
    const int rowbase = blockIdx.x * 128 + wv * 64;

    // stage 64 rows (1024 float4) coalesced; clamp OOB rows (stores guarded later)
    for (int m = 0; m < 16; ++m) {
        int f  = m * 64 + ln;          // float4 index within the 64x64 tile
        int r  = f >> 4, c4 = f & 15;
        long gr = rowbase + r; if (gr >= n) gr = n - 1;
        float4 v = ((const float4*)X)[gr * 16 + c4];
        xs[wv][r][c4 * 4 + 0] = v.x;
        xs[wv][r][c4 * 4 + 1] = v.y;
        xs[wv][r][c4 * 4 + 2] = v.z;
        xs[wv][r][c4 * 4 + 3] = v.w;
    }
    __syncthreads();

    float acc[64];
#pragma unroll
    for (int j = 0; j < 64; ++j) acc[j] = 0.f;

    for (int k = 0; k < 64; ++k) {
        float xv = xs[wv][ln][k];      // bank = (ln+k)%32 -> conflict-free
#pragma unroll
        for (int j = 0; j < 64; ++j)
            acc[j] = fmaf(xv, Wm[k * 64 + j], acc[j]);   // Wm uniform -> SGPR
    }

    int row = rowbase + ln;
    if (row < n) {
#pragma unroll
        for (int q = 0; q < 16; ++q) {
            float4 v = make_float4(acc[4*q], acc[4*q+1], acc[4*q+2], acc[4*q+3]);
            ((float4*)Y)[(long)row * 16 + q] = v;
        }
    }
}

// ---------------- scatter: atomic COO aggregation ----------------
// One float4 (16B) of one edge per thread-iteration: 16 threads cover an edge's
// 64 floats. Gathers from tw (L3-resident), scatters with HW f32 atomics.
__global__ __launch_bounds__(256) void scatter(const float* __restrict__ twI,
                                               const float* __restrict__ twU,
                                               const float* __restrict__ vals,
                                               const int*   __restrict__ rows,
                                               const int*   __restrict__ cols,
                                               float* __restrict__ uT,
                                               float* __restrict__ iT) {
    const int total16 = BB * EE * 16;
    int tid    = blockIdx.x * blockDim.x + threadIdx.x;
    int stride = gridDim.x * blockDim.x;
    for (int t = tid; t < total16; t += stride) {
        int g = t >> 4;               // global edge index in [0, B*E)
        int q = t & 15;               // float4 slot within the D=64 row
        float val = vals[g];
        int u  = rows[g];
        int it = cols[g];
        int b  = (g >= EE) ? 1 : 0;

        float4 xv = ((const float4*)twI)[(long)it * 16 + q];
        float4 yv = ((const float4*)twU)[(long)u  * 16 + q];

        float* ud = uT + ((long)b * U_N + u)  * 64 + q * 4;
        float* id = iT + ((long)b * I_N + it) * 64 + q * 4;

        unsafeAtomicAdd(ud + 0, val * xv.x);
        unsafeAtomicAdd(ud + 1, val * xv.y);
        unsafeAtomicAdd(ud + 2, val * xv.z);
        unsafeAtomicAdd(ud + 3, val * xv.w);

        unsafeAtomicAdd(id + 0, val * yv.x);
        unsafeAtomicAdd(id + 1, val * yv.y);
        unsafeAtomicAdd(id + 2, val * yv.z);
        unsafeAtomicAdd(id + 3, val * yv.w);
    }
}

// ---------------- epilogue: sigmoid(t_b) in-place + sigmoid(mean_b) ----------------
__device__ __forceinline__ float sig(float x) { return 1.f / (1.f + expf(-x)); }
__device__ __forceinline__ float4 sig4(float4 v) {
    return make_float4(sig(v.x), sig(v.y), sig(v.z), sig(v.w));
}

__global__ __launch_bounds__(256) void epilogue(float* __restrict__ out) {
    const int UD4 = U_N * DD / 4;     // 6.4M float4 per [U,D] panel
    float4* o4 = (float4*)out;
    int tid    = blockIdx.x * blockDim.x + threadIdx.x;
    int stride = gridDim.x * blockDim.x;
    for (int t = tid; t < 2 * UD4; t += stride) {
        int side = (t >= UD4) ? 1 : 0;           // 0 = users, 1 = items
        int idx  = t - side * UD4;
        long tb  = 2L * UD4 + (long)side * 2 * UD4 + idx;  // b=0 slot of this side
        float4 t0 = o4[tb];
        float4 t1 = o4[tb + UD4];
        float4 tm = make_float4(0.5f * (t0.x + t1.x), 0.5f * (t0.y + t1.y),
                                0.5f * (t0.z + t1.z), 0.5f * (t0.w + t1.w));
        o4[tb]        = sig4(t0);
        o4[tb + UD4]  = sig4(t1);
        o4[(long)side * UD4 + idx] = sig4(tm);   // mean output overwrites temp tw
    }
}

extern "C" void kernel_launch(void* const* d_in, const int* in_sizes, int n_in,
                              void* d_out, int out_size, void* d_ws, size_t ws_size,
                              hipStream_t stream) {
    const float* user_emb = (const float*)d_in[0];
    const float* item_emb = (const float*)d_in[1];
    const float* u_w      = (const float*)d_in[2];
    const float* i_w      = (const float*)d_in[3];
    const float* vals     = (const float*)d_in[4];
    const int*   rows     = (const int*)  d_in[5];
    const int*   cols     = (const int*)  d_in[6];

    float* out = (float*)d_out;
    const long UD = (long)U_N * DD;        // 25.6M floats
    float* tw_item = out;                  // temp in user-mean region
    float* tw_user = out + UD;             // temp in item-mean region
    float* uT      = out + 2 * UD;         // [B,U,D] accumulator / user_embeddings
    float* iT      = out + 2 * UD + (long)BB * UD;  // [B,I,D]

    // zero the two per-behavior accumulator regions (poisoned 0xAA each call)
    hipMemsetAsync(uT, 0, (size_t)2 * BB * UD * sizeof(float), stream);

    // tw = emb @ W   (A·X)@W == A·(X@W)
    rowgemm<<<(I_N + 127) / 128, 128, 0, stream>>>(item_emb, u_w, tw_item, I_N);
    rowgemm<<<(U_N + 127) / 128, 128, 0, stream>>>(user_emb, i_w, tw_user, U_N);

    // COO scatter with HW f32 atomics
    scatter<<<16384, 256, 0, stream>>>(tw_item, tw_user, vals, rows, cols, uT, iT);

    // sigmoid epilogue + behavior mean (overwrites tw temp regions)
    epilogue<<<8192, 256, 0, stream>>>(out);
}

// Round 4
// 6580.916 us; speedup vs baseline: 1.1832x; 1.1832x over previous
//
#include <hip/hip_runtime.h>

#define U_N 400000
#define I_N 400000
#define DD  64
#define BB  2
#define EE  2000000

// d_out float layout (all f32):
//   [0,              U*D)               user_embedding (mean)   <- temp tw_item (read-only for accum)
//   [U*D,            2*U*D)             item_embedding (mean)   <- temp tw_user (read-only for accum)
//   [2*U*D,          2*U*D + B*U*D)     user_embeddings [B,U,D] (raw sums until epilogue)
//   [2*U*D + B*U*D,  2*U*D + 2*B*U*D)   item_embeddings [B,I,D]
//
// d_ws layout (when ws_size >= 20.8MB):
//   int counts[400k]; int base[400k]; int cursor[400k]; float2 payload[2M]
// Reused for each of the 4 (direction, behavior) counting sorts.

// ---------------- tw = X @ W  (X:[n,64] f32, W:[64,64] f32) ----------------
__global__ __launch_bounds__(128) void rowgemm(const float* __restrict__ X,
                                               const float* __restrict__ Wm,
                                               float* __restrict__ Y, int n) {
    __shared__ float xs[2][64][65];
    const int wv = threadIdx.x >> 6;
    const int ln = threadIdx.x & 63;
    const int rowbase = blockIdx.x * 128 + wv * 64;

    for (int m = 0; m < 16; ++m) {
        int f  = m * 64 + ln;
        int r  = f >> 4, c4 = f & 15;
        long gr = rowbase + r; if (gr >= n) gr = n - 1;
        float4 v = ((const float4*)X)[gr * 16 + c4];
        xs[wv][r][c4 * 4 + 0] = v.x;
        xs[wv][r][c4 * 4 + 1] = v.y;
        xs[wv][r][c4 * 4 + 2] = v.z;
        xs[wv][r][c4 * 4 + 3] = v.w;
    }
    __syncthreads();

    float acc[64];
#pragma unroll
    for (int j = 0; j < 64; ++j) acc[j] = 0.f;

    for (int k = 0; k < 64; ++k) {
        float xv = xs[wv][ln][k];
#pragma unroll
        for (int j = 0; j < 64; ++j)
            acc[j] = fmaf(xv, Wm[k * 64 + j], acc[j]);   // Wm uniform -> SGPR
    }

    int row = rowbase + ln;
    if (row < n) {
#pragma unroll
        for (int q = 0; q < 16; ++q) {
            float4 v = make_float4(acc[4*q], acc[4*q+1], acc[4*q+2], acc[4*q+3]);
            ((float4*)Y)[(long)row * 16 + q] = v;
        }
    }
}

// ---------------- counting sort by destination ----------------
__global__ __launch_bounds__(256) void hist_kernel(const int* __restrict__ idx,
                                                   int* __restrict__ counts) {
    int tid = blockIdx.x * blockDim.x + threadIdx.x;
    int stride = gridDim.x * blockDim.x;
    for (int e = tid; e < EE; e += stride) atomicAdd(&counts[idx[e]], 1);
}

// single-block exclusive scan over n counts -> base (and cursor copy)
#define SCAN_T 1024
__global__ __launch_bounds__(SCAN_T) void scan_kernel(const int* __restrict__ counts,
                                                      int* __restrict__ base,
                                                      int* __restrict__ cursor, int n) {
    __shared__ int ssum[SCAN_T];
    const int ch = (n + SCAN_T - 1) / SCAN_T;
    int t = threadIdx.x;
    int lo = t * ch; int hi = min(lo + ch, n);
    int s = 0;
    for (int i = lo; i < hi; ++i) s += counts[i];
    ssum[t] = s; __syncthreads();
    for (int off = 1; off < SCAN_T; off <<= 1) {
        int v = (t >= off) ? ssum[t - off] : 0;
        __syncthreads();
        ssum[t] += v;
        __syncthreads();
    }
    int run = ssum[t] - s;                       // exclusive prefix of this chunk
    for (int i = lo; i < hi; ++i) {
        int c = counts[i];
        base[i] = run; cursor[i] = run; run += c;
    }
}

// scatter (val, src) into destination-sorted payload order
__global__ __launch_bounds__(256) void place_kernel(const int* __restrict__ idx,
                                                    const int* __restrict__ src,
                                                    const float* __restrict__ vals,
                                                    int* __restrict__ cursor,
                                                    float2* __restrict__ payload) {
    int tid = blockIdx.x * blockDim.x + threadIdx.x;
    int stride = gridDim.x * blockDim.x;
    for (int e = tid; e < EE; e += stride) {
        int d = idx[e];
        int p = atomicAdd(&cursor[d], 1);
        payload[p] = make_float2(vals[e], __int_as_float(src[e]));
    }
}

// one wave per destination row: register accumulate, single coalesced store
__global__ __launch_bounds__(256) void accum_kernel(const float2* __restrict__ payload,
                                                    const int* __restrict__ base,
                                                    const int* __restrict__ counts,
                                                    const float* __restrict__ tw,
                                                    float* __restrict__ outp, int n) {
    int wid  = (blockIdx.x * blockDim.x + threadIdx.x) >> 6;
    int lane = threadIdx.x & 63;
    if (wid >= n) return;
    int st = base[wid], cnt = counts[wid];
    float acc = 0.f;
    for (int k = 0; k < cnt; ++k) {
        float2 p = payload[st + k];              // same addr all lanes -> broadcast
        int s = __float_as_int(p.y);
        acc += p.x * tw[(long)s * 64 + lane];    // 256B coalesced gather
    }
    outp[(long)wid * 64 + lane] = acc;           // 256B coalesced store, no atomics
}

// ---------------- fallback: atomic COO scatter (ws too small) ----------------
__global__ __launch_bounds__(256) void scatter(const float* __restrict__ twI,
                                               const float* __restrict__ twU,
                                               const float* __restrict__ vals,
                                               const int*   __restrict__ rows,
                                               const int*   __restrict__ cols,
                                               float* __restrict__ uT,
                                               float* __restrict__ iT) {
    const int total16 = BB * EE * 16;
    int tid    = blockIdx.x * blockDim.x + threadIdx.x;
    int stride = gridDim.x * blockDim.x;
    for (int t = tid; t < total16; t += stride) {
        int g = t >> 4;
        int q = t & 15;
        float val = vals[g];
        int u  = rows[g];
        int it = cols[g];
        int b  = (g >= EE) ? 1 : 0;
        float4 xv = ((const float4*)twI)[(long)it * 16 + q];
        float4 yv = ((const float4*)twU)[(long)u  * 16 + q];
        float* ud = uT + ((long)b * U_N + u)  * 64 + q * 4;
        float* id = iT + ((long)b * I_N + it) * 64 + q * 4;
        unsafeAtomicAdd(ud + 0, val * xv.x);
        unsafeAtomicAdd(ud + 1, val * xv.y);
        unsafeAtomicAdd(ud + 2, val * xv.z);
        unsafeAtomicAdd(ud + 3, val * xv.w);
        unsafeAtomicAdd(id + 0, val * yv.x);
        unsafeAtomicAdd(id + 1, val * yv.y);
        unsafeAtomicAdd(id + 2, val * yv.z);
        unsafeAtomicAdd(id + 3, val * yv.w);
    }
}

// ---------------- epilogue: sigmoid(t_b) in-place + sigmoid(mean_b) ----------------
__device__ __forceinline__ float sig(float x) { return 1.f / (1.f + expf(-x)); }
__device__ __forceinline__ float4 sig4(float4 v) {
    return make_float4(sig(v.x), sig(v.y), sig(v.z), sig(v.w));
}

__global__ __launch_bounds__(256) void epilogue(float* __restrict__ out) {
    const int UD4 = U_N * DD / 4;
    float4* o4 = (float4*)out;
    int tid    = blockIdx.x * blockDim.x + threadIdx.x;
    int stride = gridDim.x * blockDim.x;
    for (int t = tid; t < 2 * UD4; t += stride) {
        int side = (t >= UD4) ? 1 : 0;
        int idx  = t - side * UD4;
        long tb  = 2L * UD4 + (long)side * 2 * UD4 + idx;
        float4 t0 = o4[tb];
        float4 t1 = o4[tb + UD4];
        float4 tm = make_float4(0.5f * (t0.x + t1.x), 0.5f * (t0.y + t1.y),
                                0.5f * (t0.z + t1.z), 0.5f * (t0.w + t1.w));
        o4[tb]        = sig4(t0);
        o4[tb + UD4]  = sig4(t1);
        o4[(long)side * UD4 + idx] = sig4(tm);
    }
}

extern "C" void kernel_launch(void* const* d_in, const int* in_sizes, int n_in,
                              void* d_out, int out_size, void* d_ws, size_t ws_size,
                              hipStream_t stream) {
    const float* user_emb = (const float*)d_in[0];
    const float* item_emb = (const float*)d_in[1];
    const float* u_w      = (const float*)d_in[2];
    const float* i_w      = (const float*)d_in[3];
    const float* vals     = (const float*)d_in[4];
    const int*   rows     = (const int*)  d_in[5];
    const int*   cols     = (const int*)  d_in[6];

    float* out = (float*)d_out;
    const long UD = (long)U_N * DD;
    float* tw_item = out;                           // user-mean region (temp)
    float* tw_user = out + UD;                      // item-mean region (temp)
    float* uT      = out + 2 * UD;                  // [B,U,D]
    float* iT      = out + 2 * UD + (long)BB * UD;  // [B,I,D]

    // tw = emb @ W   ((A·X)@W == A·(X@W))
    rowgemm<<<(I_N + 127) / 128, 128, 0, stream>>>(item_emb, u_w, tw_item, I_N);
    rowgemm<<<(U_N + 127) / 128, 128, 0, stream>>>(user_emb, i_w, tw_user, U_N);

    const size_t need = (size_t)3 * 400000 * sizeof(int) + (size_t)EE * sizeof(float2);
    if (ws_size >= need) {
        int*    counts  = (int*)d_ws;
        int*    base    = counts + 400000;
        int*    cursor  = base   + 400000;
        float2* payload = (float2*)(cursor + 400000);

        // 4 passes: (dir, behavior). dir=0: dest=rows (users), src=cols, tw_item.
        //           dir=1: dest=cols (items), src=rows, tw_user.
        for (int pass = 0; pass < 4; ++pass) {
            int dir = pass >> 1, b = pass & 1;
            const int*   idx = (dir == 0 ? rows : cols) + (long)b * EE;
            const int*   sr  = (dir == 0 ? cols : rows) + (long)b * EE;
            const float* vv  = vals + (long)b * EE;
            const float* tw  = dir == 0 ? tw_item : tw_user;
            float*       op  = (dir == 0 ? uT : iT) + (long)b * U_N * DD;

            hipMemsetAsync(counts, 0, 400000 * sizeof(int), stream);
            hist_kernel <<<2048, 256, 0, stream>>>(idx, counts);
            scan_kernel <<<1, SCAN_T, 0, stream>>>(counts, base, cursor, 400000);
            place_kernel<<<2048, 256, 0, stream>>>(idx, sr, vv, cursor, payload);
            accum_kernel<<<100000, 256, 0, stream>>>(payload, base, counts, tw, op, 400000);
        }
    } else {
        // fallback: atomic scatter
        hipMemsetAsync(uT, 0, (size_t)2 * BB * UD * sizeof(float), stream);
        scatter<<<16384, 256, 0, stream>>>(tw_item, tw_user, vals, rows, cols, uT, iT);
    }

    epilogue<<<8192, 256, 0, stream>>>(out);
}